// Round 1
// baseline (2817.167 us; speedup 1.0000x reference)
//
#include <hip/hip_runtime.h>
#include <math.h>

#define B_ 32
#define F_ 128
#define H_ 256
#define N_ 2048
#define L_ 2
#define E_ 262144
#define NN_ 65536          // B_*N_
// DEG = E/(B*N) = 4

// ---------------- small kernels ----------------

// h0[b][j] = b_in[j] + sum_k x[b][k]*W_in[k][j]   (32x128 @ 128x256)
__global__ void h0_kernel(const float* __restrict__ x, const float* __restrict__ W_in,
                          const float* __restrict__ b_in, float* __restrict__ h0) {
  int b = blockIdx.x;
  int j = threadIdx.x;
  float acc = b_in[j];
#pragma unroll 8
  for (int k = 0; k < F_; ++k)
    acc += x[b * F_ + k] * W_in[k * H_ + j];
  h0[b * H_ + j] = acc;
}

// mean_d[i] = (1/(N-1)) * sum_j ||p_i - p_j||  (j==i term is 0, matches masked ref)
__global__ void meand_kernel(const float* __restrict__ positions, float* __restrict__ mean_d) {
  __shared__ float red[256];
  int i = blockIdx.x;
  int t = threadIdx.x;
  float px = positions[i * 3 + 0], py = positions[i * 3 + 1], pz = positions[i * 3 + 2];
  float s = 0.f;
  for (int j = t; j < N_; j += 256) {
    float dx = px - positions[j * 3 + 0];
    float dy = py - positions[j * 3 + 1];
    float dz = pz - positions[j * 3 + 2];
    s += sqrtf(dx * dx + dy * dy + dz * dz);
  }
  red[t] = s;
  __syncthreads();
  for (int off = 128; off > 0; off >>= 1) {
    if (t < off) red[t] += red[t + off];
    __syncthreads();
  }
  if (t == 0) mean_d[i] = red[0] / (float)(N_ - 1);
}

// g[n][j] = bg2[j] + sum_k relu(mean_d[n]*(Wg1[0][k]+Wg1[1][k]+Wg1[2][k]) + bg1[k]) * Wg2[k][j]
__global__ void g_kernel(const float* __restrict__ mean_d,
                         const float* __restrict__ Wg1, const float* __restrict__ bg1,
                         const float* __restrict__ Wg2, const float* __restrict__ bg2,
                         float* __restrict__ g) {
  __shared__ float hid[128];
  int n = blockIdx.x;
  int t = threadIdx.x;
  float md = mean_d[n];
  if (t < 128) {
    float w = Wg1[t] + Wg1[128 + t] + Wg1[256 + t];
    hid[t] = fmaxf(md * w + bg1[t], 0.f);
  }
  __syncthreads();
  float acc = bg2[t];
#pragma unroll 8
  for (int k = 0; k < 128; ++k)
    acc += hid[k] * Wg2[k * H_ + t];
  g[n * H_ + t] = acc;
}

// h[b*N+n][:] = h0[b][:] + g[n][:]   (vectorized float4; one float4 per thread)
__global__ void hinit_kernel(const float* __restrict__ h0, const float* __restrict__ g,
                             float* __restrict__ h) {
  int idx = blockIdx.x * blockDim.x + threadIdx.x;  // float4 index, NN_*64 total
  int row = idx >> 6;
  int c4 = (idx & 63) << 2;
  const float4 a = *(const float4*)(h0 + (row >> 11) * H_ + c4);
  const float4 b = *(const float4*)(g + (row & (N_ - 1)) * H_ + c4);
  float4 r;
  r.x = a.x + b.x; r.y = a.y + b.y; r.z = a.z + b.z; r.w = a.w + b.w;
  *(float4*)(h + row * H_ + c4) = r;
}

// pos[b*N+n][c] = positions[n][c]
__global__ void posinit_kernel(const float* __restrict__ positions, float* __restrict__ pos) {
  int i = blockIdx.x * blockDim.x + threadIdx.x;  // 0 .. NN_*3-1
  int row = i / 3;
  int c = i - row * 3;
  pos[i] = positions[(row & (N_ - 1)) * 3 + c];
}

// pos += posdelta / DEG
__global__ void posupd_kernel(float* __restrict__ pos, const float* __restrict__ pd) {
  int i = blockIdx.x * blockDim.x + threadIdx.x;
  pos[i] += pd[i] * 0.25f;
}

// out[i] = b_out + dot(h[i], W_out)  — one wave per node
__global__ void out_kernel(const float* __restrict__ h, const float* __restrict__ Wout,
                           const float* __restrict__ bout, float* __restrict__ out) {
  int gid = blockIdx.x * blockDim.x + threadIdx.x;
  int node = gid >> 6;
  int lane = gid & 63;
  const float4 hv = *(const float4*)(h + node * H_ + (lane << 2));
  const float4 wv = *(const float4*)(Wout + (lane << 2));
  float p = hv.x * wv.x + hv.y * wv.y + hv.z * wv.z + hv.w * wv.w;
#pragma unroll
  for (int m = 1; m < 64; m <<= 1) p += __shfl_xor(p, m, 64);
  if (lane == 0) out[node] = p + bout[0];
}

// ---------------- message kernel ----------------
// Tile: 32 edges x 256 outputs per block, K=513 in 16 chunks of 32 (+ the d-row).
// A[e, 0:256]=h[src], A[e,256:512]=h[dst], A[e,512]=d_e.
// After GEMM: relu(+bm), coef=m@Wp (wave butterfly), atomic agg & posdelta.
__launch_bounds__(256, 4)
__global__ void msg_kernel(const float* __restrict__ h, const float* __restrict__ pos,
                           const int* __restrict__ ei,
                           const float* __restrict__ Wm, const float* __restrict__ bm,
                           const float* __restrict__ Wp,
                           float* __restrict__ agg, float* __restrict__ posdelta) {
  __shared__ float sW[32][256];   // 32 KB
  __shared__ float sA[32][36];    // transposed A tile: sA[k][e], pad 36 keeps 16B align
  __shared__ float sD[32];
  __shared__ float sDv[3][32];
  __shared__ int sSrc[32];
  __shared__ int sDst[32];

  const int t = threadIdx.x;
  const int e0 = blockIdx.x << 5;

  if (t < 32) {
    int s = ei[e0 + t];
    int d = ei[E_ + e0 + t];
    sSrc[t] = s;
    sDst[t] = d;
    float dx = pos[d * 3 + 0] - pos[s * 3 + 0];
    float dy = pos[d * 3 + 1] - pos[s * 3 + 1];
    float dz = pos[d * 3 + 2] - pos[s * 3 + 2];
    sDv[0][t] = dx; sDv[1][t] = dy; sDv[2][t] = dz;
    sD[t] = sqrtf(dx * dx + dy * dy + dz * dz + 1e-12f);
  }
  __syncthreads();

  const int te = t >> 6;              // wave id: edges te*8..te*8+7
  const int tj = t & 63;              // outputs tj*4..tj*4+3
  const int ee_ld = t >> 3;           // staging: edge row 0..31
  const int k4_ld = (t & 7) << 2;     // staging: k offset 0,4,..,28

  float acc[8][4];
#pragma unroll
  for (int i = 0; i < 8; ++i) { acc[i][0] = 0.f; acc[i][1] = 0.f; acc[i][2] = 0.f; acc[i][3] = 0.f; }

  const int rs = sSrc[ee_ld];
  const int rd = sDst[ee_ld];

  for (int kc = 0; kc < 16; ++kc) {
    // stage A: one float4 gather per thread (1024 floats = 32 edges x 32 k)
    int kg = (kc << 5) + k4_ld;
    int row = (kg < 256) ? rs : rd;
    const float4 v = *(const float4*)(h + row * H_ + (kg & 255));
    sA[k4_ld + 0][ee_ld] = v.x;
    sA[k4_ld + 1][ee_ld] = v.y;
    sA[k4_ld + 2][ee_ld] = v.z;
    sA[k4_ld + 3][ee_ld] = v.w;
    // stage W: 8 float4 per thread, coalesced
    const float* Wsrc = Wm + (kc << 5) * H_;
#pragma unroll
    for (int it = 0; it < 8; ++it) {
      int idx = (it << 8) + t;
      int r = idx >> 6, cc = (idx & 63) << 2;
      *(float4*)&sW[r][cc] = *(const float4*)(Wsrc + r * H_ + cc);
    }
    __syncthreads();
#pragma unroll
    for (int k = 0; k < 32; ++k) {
      float a[8];
      *(float4*)&a[0] = *(const float4*)&sA[k][te * 8];      // broadcast across wave
      *(float4*)&a[4] = *(const float4*)&sA[k][te * 8 + 4];  // broadcast across wave
      const float4 w = *(const float4*)&sW[k][tj << 2];
#pragma unroll
      for (int i = 0; i < 8; ++i) {
        acc[i][0] += a[i] * w.x;
        acc[i][1] += a[i] * w.y;
        acc[i][2] += a[i] * w.z;
        acc[i][3] += a[i] * w.w;
      }
    }
    __syncthreads();
  }

  // k=512 (distance row) + bias + relu; coef partials
  const float4 wl  = *(const float4*)(Wm + 512 * H_ + (tj << 2));
  const float4 bmv = *(const float4*)(bm + (tj << 2));
  const float4 wpv = *(const float4*)(Wp + (tj << 2));

  float c[8][4];
  float coef[8];
#pragma unroll
  for (int i = 0; i < 8; ++i) {
    float dv = sD[te * 8 + i];
    c[i][0] = fmaxf(acc[i][0] + dv * wl.x + bmv.x, 0.f);
    c[i][1] = fmaxf(acc[i][1] + dv * wl.y + bmv.y, 0.f);
    c[i][2] = fmaxf(acc[i][2] + dv * wl.z + bmv.z, 0.f);
    c[i][3] = fmaxf(acc[i][3] + dv * wl.w + bmv.w, 0.f);
    coef[i] = c[i][0] * wpv.x + c[i][1] * wpv.y + c[i][2] * wpv.z + c[i][3] * wpv.w;
  }
  // full-wave butterfly: every lane ends with coef = m_e @ Wp
#pragma unroll
  for (int m = 1; m < 64; m <<= 1) {
#pragma unroll
    for (int i = 0; i < 8; ++i) coef[i] += __shfl_xor(coef[i], m, 64);
  }
  // scatter: agg[dst] += m ; posdelta[dst] += (pos[dst]-pos[src]) * coef
#pragma unroll
  for (int i = 0; i < 8; ++i) {
    int dn = sDst[te * 8 + i];
    float* ap = agg + dn * H_ + (tj << 2);
    atomicAdd(ap + 0, c[i][0]);
    atomicAdd(ap + 1, c[i][1]);
    atomicAdd(ap + 2, c[i][2]);
    atomicAdd(ap + 3, c[i][3]);
  }
  if (tj < 3) {
#pragma unroll
    for (int i = 0; i < 8; ++i) {
      int idx = te * 8 + i;
      atomicAdd(&posdelta[sDst[idx] * 3 + tj], sDv[tj][idx] * coef[i]);
    }
  }
}

// ---------------- node update kernel ----------------
// h[m] += relu([h[m] | agg[m]] @ Wu + bu). In-place safe: block only touches own rows.
__launch_bounds__(256, 4)
__global__ void upd_kernel(float* __restrict__ h, const float* __restrict__ agg,
                           const float* __restrict__ Wu, const float* __restrict__ bu) {
  __shared__ float sW[32][256];
  __shared__ float sA[32][36];

  const int t = threadIdx.x;
  const int m0 = blockIdx.x << 5;
  const int te = t >> 6;
  const int tj = t & 63;
  const int ee_ld = t >> 3;
  const int k4_ld = (t & 7) << 2;

  float acc[8][4];
#pragma unroll
  for (int i = 0; i < 8; ++i) { acc[i][0] = 0.f; acc[i][1] = 0.f; acc[i][2] = 0.f; acc[i][3] = 0.f; }

  const int row_ld = m0 + ee_ld;

  for (int kc = 0; kc < 16; ++kc) {
    int kg = (kc << 5) + k4_ld;
    const float* src = (kg < 256) ? h : agg;
    const float4 v = *(const float4*)(src + row_ld * H_ + (kg & 255));
    sA[k4_ld + 0][ee_ld] = v.x;
    sA[k4_ld + 1][ee_ld] = v.y;
    sA[k4_ld + 2][ee_ld] = v.z;
    sA[k4_ld + 3][ee_ld] = v.w;
    const float* Wsrc = Wu + (kc << 5) * H_;
#pragma unroll
    for (int it = 0; it < 8; ++it) {
      int idx = (it << 8) + t;
      int r = idx >> 6, cc = (idx & 63) << 2;
      *(float4*)&sW[r][cc] = *(const float4*)(Wsrc + r * H_ + cc);
    }
    __syncthreads();
#pragma unroll
    for (int k = 0; k < 32; ++k) {
      float a[8];
      *(float4*)&a[0] = *(const float4*)&sA[k][te * 8];
      *(float4*)&a[4] = *(const float4*)&sA[k][te * 8 + 4];
      const float4 w = *(const float4*)&sW[k][tj << 2];
#pragma unroll
      for (int i = 0; i < 8; ++i) {
        acc[i][0] += a[i] * w.x;
        acc[i][1] += a[i] * w.y;
        acc[i][2] += a[i] * w.z;
        acc[i][3] += a[i] * w.w;
      }
    }
    __syncthreads();
  }

  const float4 buv = *(const float4*)(bu + (tj << 2));
#pragma unroll
  for (int i = 0; i < 8; ++i) {
    float* hp = h + (m0 + te * 8 + i) * H_ + (tj << 2);
    float4 hv = *(float4*)hp;
    hv.x += fmaxf(acc[i][0] + buv.x, 0.f);
    hv.y += fmaxf(acc[i][1] + buv.y, 0.f);
    hv.z += fmaxf(acc[i][2] + buv.z, 0.f);
    hv.w += fmaxf(acc[i][3] + buv.w, 0.f);
    *(float4*)hp = hv;
  }
}

// ---------------- launcher ----------------

extern "C" void kernel_launch(void* const* d_in, const int* in_sizes, int n_in,
                              void* d_out, int out_size, void* d_ws, size_t ws_size,
                              hipStream_t stream) {
  const float* x         = (const float*)d_in[0];
  const float* positions = (const float*)d_in[1];
  const float* W_in      = (const float*)d_in[2];
  const float* b_in      = (const float*)d_in[3];
  const float* Wg1       = (const float*)d_in[4];
  const float* bg1       = (const float*)d_in[5];
  const float* Wg2       = (const float*)d_in[6];
  const float* bg2       = (const float*)d_in[7];
  const float* Wm        = (const float*)d_in[8];
  const float* bm        = (const float*)d_in[9];
  const float* Wu        = (const float*)d_in[10];
  const float* bu        = (const float*)d_in[11];
  const float* Wp        = (const float*)d_in[12];
  const float* W_out     = (const float*)d_in[13];
  const float* b_out     = (const float*)d_in[14];
  const int*   ei        = (const int*)d_in[15];
  float* out = (float*)d_out;

  // workspace layout (bytes): h 64MB | agg 64MB | pos 768KB | pd 768KB | g 2MB | h0 32KB | md 8KB
  char* ws = (char*)d_ws;
  float* h   = (float*)(ws);
  float* agg = (float*)(ws + 67108864UL);
  float* pos = (float*)(ws + 134217728UL);
  float* pd  = (float*)(ws + 135004160UL);
  float* g   = (float*)(ws + 135790592UL);
  float* h0  = (float*)(ws + 137887744UL);
  float* md  = (float*)(ws + 137920512UL);

  h0_kernel<<<B_, 256, 0, stream>>>(x, W_in, b_in, h0);
  meand_kernel<<<N_, 256, 0, stream>>>(positions, md);
  g_kernel<<<N_, 256, 0, stream>>>(md, Wg1, bg1, Wg2, bg2, g);
  hinit_kernel<<<NN_ * 64 / 256, 256, 0, stream>>>(h0, g, h);
  posinit_kernel<<<NN_ * 3 / 256, 256, 0, stream>>>(positions, pos);

  for (int l = 0; l < L_; ++l) {
    hipMemsetAsync(agg, 0, (size_t)NN_ * H_ * sizeof(float), stream);
    hipMemsetAsync(pd, 0, (size_t)NN_ * 3 * sizeof(float), stream);
    msg_kernel<<<E_ / 32, 256, 0, stream>>>(h, pos, ei, Wm + l * 513 * H_, bm + l * H_,
                                            Wp + l * H_, agg, pd);
    posupd_kernel<<<NN_ * 3 / 256, 256, 0, stream>>>(pos, pd);
    upd_kernel<<<NN_ / 32, 256, 0, stream>>>(h, agg, Wu + l * 512 * H_, bu + l * H_);
  }

  out_kernel<<<NN_ * 64 / 256, 256, 0, stream>>>(h, W_out, b_out, out);
}

// Round 2
// 846.704 us; speedup vs baseline: 3.3272x; 3.3272x over previous
//
#include <hip/hip_runtime.h>
#include <math.h>

#define B_ 32
#define F_ 128
#define H_ 256
#define N_ 2048
#define L_ 2
#define E_ 262144
#define NN_ 65536          // B_*N_
// DEG = E/(B*N) = 4

typedef __attribute__((ext_vector_type(8))) short short8;   // 8 bf16 = 4 VGPRs (MFMA A/B frag)
typedef __attribute__((ext_vector_type(4))) float f32x4;    // MFMA C/D frag

static __device__ __forceinline__ unsigned short f2bf(float f) {
  unsigned int u = __float_as_uint(f);
  u += 0x7FFF + ((u >> 16) & 1);      // round-to-nearest-even
  return (unsigned short)(u >> 16);
}

// ---------------- small kernels (unchanged from round 1) ----------------

__global__ void h0_kernel(const float* __restrict__ x, const float* __restrict__ W_in,
                          const float* __restrict__ b_in, float* __restrict__ h0) {
  int b = blockIdx.x;
  int j = threadIdx.x;
  float acc = b_in[j];
#pragma unroll 8
  for (int k = 0; k < F_; ++k)
    acc += x[b * F_ + k] * W_in[k * H_ + j];
  h0[b * H_ + j] = acc;
}

__global__ void meand_kernel(const float* __restrict__ positions, float* __restrict__ mean_d) {
  __shared__ float red[256];
  int i = blockIdx.x;
  int t = threadIdx.x;
  float px = positions[i * 3 + 0], py = positions[i * 3 + 1], pz = positions[i * 3 + 2];
  float s = 0.f;
  for (int j = t; j < N_; j += 256) {
    float dx = px - positions[j * 3 + 0];
    float dy = py - positions[j * 3 + 1];
    float dz = pz - positions[j * 3 + 2];
    s += sqrtf(dx * dx + dy * dy + dz * dz);
  }
  red[t] = s;
  __syncthreads();
  for (int off = 128; off > 0; off >>= 1) {
    if (t < off) red[t] += red[t + off];
    __syncthreads();
  }
  if (t == 0) mean_d[i] = red[0] / (float)(N_ - 1);
}

__global__ void g_kernel(const float* __restrict__ mean_d,
                         const float* __restrict__ Wg1, const float* __restrict__ bg1,
                         const float* __restrict__ Wg2, const float* __restrict__ bg2,
                         float* __restrict__ g) {
  __shared__ float hid[128];
  int n = blockIdx.x;
  int t = threadIdx.x;
  float md = mean_d[n];
  if (t < 128) {
    float w = Wg1[t] + Wg1[128 + t] + Wg1[256 + t];
    hid[t] = fmaxf(md * w + bg1[t], 0.f);
  }
  __syncthreads();
  float acc = bg2[t];
#pragma unroll 8
  for (int k = 0; k < 128; ++k)
    acc += hid[k] * Wg2[k * H_ + t];
  g[n * H_ + t] = acc;
}

__global__ void hinit_kernel(const float* __restrict__ h0, const float* __restrict__ g,
                             float* __restrict__ h) {
  int idx = blockIdx.x * blockDim.x + threadIdx.x;
  int row = idx >> 6;
  int c4 = (idx & 63) << 2;
  const float4 a = *(const float4*)(h0 + (row >> 11) * H_ + c4);
  const float4 b = *(const float4*)(g + (row & (N_ - 1)) * H_ + c4);
  float4 r;
  r.x = a.x + b.x; r.y = a.y + b.y; r.z = a.z + b.z; r.w = a.w + b.w;
  *(float4*)(h + row * H_ + c4) = r;
}

__global__ void posinit_kernel(const float* __restrict__ positions, float* __restrict__ pos) {
  int i = blockIdx.x * blockDim.x + threadIdx.x;
  int row = i / 3;
  int c = i - row * 3;
  pos[i] = positions[(row & (N_ - 1)) * 3 + c];
}

__global__ void posupd_kernel(float* __restrict__ pos, const float* __restrict__ pd) {
  int i = blockIdx.x * blockDim.x + threadIdx.x;
  pos[i] += pd[i] * 0.25f;
}

__global__ void out_kernel(const float* __restrict__ h, const float* __restrict__ Wout,
                           const float* __restrict__ bout, float* __restrict__ out) {
  int gid = blockIdx.x * blockDim.x + threadIdx.x;
  int node = gid >> 6;
  int lane = gid & 63;
  const float4 hv = *(const float4*)(h + node * H_ + (lane << 2));
  const float4 wv = *(const float4*)(Wout + (lane << 2));
  float p = hv.x * wv.x + hv.y * wv.y + hv.z * wv.z + hv.w * wv.w;
#pragma unroll
  for (int m = 1; m < 64; m <<= 1) p += __shfl_xor(p, m, 64);
  if (lane == 0) out[node] = p + bout[0];
}

// ---------------- bf16 conversion kernels ----------------

// W [512][256] fp32 row-major -> Wt chunk-major [8][256][64] bf16
// Wt[(kc*256 + n)*64 + kl] = bf16(W[(kc*64+kl)*256 + n])
__global__ void wconv_kernel(const float* __restrict__ W, unsigned short* __restrict__ Wt) {
  int idx = blockIdx.x * blockDim.x + threadIdx.x;   // 131072
  int kc = idx >> 14;
  int rem = idx & 16383;
  int n = rem >> 6;
  int kl = rem & 63;
  Wt[idx] = f2bf(W[(kc * 64 + kl) * H_ + n]);
}

// h fp32 -> hbf bf16 (flat NN*256)
__global__ void hbf_kernel(const float* __restrict__ h, unsigned short* __restrict__ hbf) {
  int i = (blockIdx.x * blockDim.x + threadIdx.x) << 3;
  const float4 a = *(const float4*)(h + i);
  const float4 b = *(const float4*)(h + i + 4);
  short8 v;
  v[0] = (short)f2bf(a.x); v[1] = (short)f2bf(a.y);
  v[2] = (short)f2bf(a.z); v[3] = (short)f2bf(a.w);
  v[4] = (short)f2bf(b.x); v[5] = (short)f2bf(b.y);
  v[6] = (short)f2bf(b.z); v[7] = (short)f2bf(b.w);
  *(short8*)(hbf + i) = v;
}

// ---------------- MFMA message kernel ----------------
// Block tile: 64 edges x 256 channels, K=512 in 8 chunks of 64.
// 4 waves; wave w -> channel slice [w*64, w*64+64), 4x4 grid of 16x16x32 mfma.
// A[e][k] = hbf[src[e]][k] (k<256) | hbf[dst[e]][k-256]; distance row in fp32 epilogue.
__launch_bounds__(256)
__global__ void msg_mfma(const unsigned short* __restrict__ hbf,
                         const float* __restrict__ pos,
                         const int* __restrict__ ei,
                         const unsigned short* __restrict__ Wt,   // [8][256][64] bf16
                         const float* __restrict__ wl,            // Wm row 512 fp32 [256]
                         const float* __restrict__ bm,
                         const float* __restrict__ Wp,
                         float* __restrict__ agg, float* __restrict__ posdelta) {
  __shared__ __align__(16) unsigned short sW[256 * 72];  // [n][kl], pad 72 (144B rows)
  __shared__ __align__(16) unsigned short sA[64 * 72];   // [e][kl]
  __shared__ float sCoef[4][64];
  __shared__ float sD[64];
  __shared__ float sDv[3][64];
  __shared__ int sSrc[64];
  __shared__ int sDst[64];

  const int t = threadIdx.x;
  const int e0 = blockIdx.x << 6;

  if (t < 64) {
    int s = ei[e0 + t], d = ei[E_ + e0 + t];
    sSrc[t] = s; sDst[t] = d;
    float dx = pos[d * 3 + 0] - pos[s * 3 + 0];
    float dy = pos[d * 3 + 1] - pos[s * 3 + 1];
    float dz = pos[d * 3 + 2] - pos[s * 3 + 2];
    sDv[0][t] = dx; sDv[1][t] = dy; sDv[2][t] = dz;
    sD[t] = sqrtf(dx * dx + dy * dy + dz * dz + 1e-12f);
  }
  __syncthreads();

  const int w = t >> 6;
  const int lane = t & 63;
  const int q = lane >> 4;      // quad group
  const int r = lane & 15;      // row-within-16

  const int eA = t >> 2;        // staging: edge row 0..63
  const int jA = t & 3;         // staging: 16-elem chunk

  f32x4 acc[4][4];
#pragma unroll
  for (int mi = 0; mi < 4; ++mi)
#pragma unroll
    for (int ni = 0; ni < 4; ++ni)
      acc[mi][ni] = (f32x4){0.f, 0.f, 0.f, 0.f};

  const int rsrc = sSrc[eA];
  const int rdst = sDst[eA];

  for (int kc = 0; kc < 8; ++kc) {
    // stage A: gather 64 edge-rows x 64 k (bf16), 32B per thread
    {
      int row = (kc < 4) ? rsrc : rdst;
      int cb = ((kc & 3) << 6) + (jA << 4);
      const unsigned short* src = hbf + (((size_t)row) << 8) + cb;
      short8 v0 = *(const short8*)(src);
      short8 v1 = *(const short8*)(src + 8);
      unsigned short* dst = sA + eA * 72 + (jA << 4);
      *(short8*)(dst) = v0;
      *(short8*)(dst + 8) = v1;
    }
    // stage W: contiguous 32KB chunk, fully coalesced
    {
      const unsigned short* src = Wt + (((size_t)kc) << 14) + (t << 3);
      const int nb = t >> 3;
      const int kb = (t & 7) << 3;
#pragma unroll
      for (int i = 0; i < 8; ++i) {
        short8 v = *(const short8*)(src + (i << 11));
        *(short8*)(sW + ((i << 5) + nb) * 72 + kb) = v;
      }
    }
    __syncthreads();
#pragma unroll
    for (int ks = 0; ks < 2; ++ks) {
      const int ko = (ks << 5) + (q << 3);
      short8 af[4], bfr[4];
#pragma unroll
      for (int mi = 0; mi < 4; ++mi)
        af[mi] = *(const short8*)(sA + (mi * 16 + r) * 72 + ko);
#pragma unroll
      for (int ni = 0; ni < 4; ++ni)
        bfr[ni] = *(const short8*)(sW + ((w << 6) + ni * 16 + r) * 72 + ko);
#pragma unroll
      for (int mi = 0; mi < 4; ++mi)
#pragma unroll
        for (int ni = 0; ni < 4; ++ni)
          acc[mi][ni] = __builtin_amdgcn_mfma_f32_16x16x32_bf16(af[mi], bfr[ni], acc[mi][ni], 0, 0, 0);
    }
    __syncthreads();
  }

  // epilogue: +d*wl + bm, relu, coef partials, atomic agg scatter
  float wlv[4], bmv[4], wpv[4];
#pragma unroll
  for (int ni = 0; ni < 4; ++ni) {
    int n = (w << 6) + ni * 16 + r;
    wlv[ni] = wl[n]; bmv[ni] = bm[n]; wpv[ni] = Wp[n];
  }
  float coefp[4][4];
#pragma unroll
  for (int mi = 0; mi < 4; ++mi)
#pragma unroll
    for (int reg = 0; reg < 4; ++reg)
      coefp[mi][reg] = 0.f;

#pragma unroll
  for (int mi = 0; mi < 4; ++mi) {
#pragma unroll
    for (int reg = 0; reg < 4; ++reg) {
      int m = mi * 16 + q * 4 + reg;     // edge row (C layout: row = quad*4+reg)
      float dv = sD[m];
      float* ap = agg + (((size_t)sDst[m]) << 8);
#pragma unroll
      for (int ni = 0; ni < 4; ++ni) {
        float v = acc[mi][ni][reg] + dv * wlv[ni] + bmv[ni];
        v = fmaxf(v, 0.f);
        coefp[mi][reg] += v * wpv[ni];
        atomicAdd(ap + ((w << 6) + ni * 16 + r), v);
      }
    }
  }
  // reduce coef over the 16 r-lanes (same q share the same edge set)
#pragma unroll
  for (int mask = 1; mask < 16; mask <<= 1)
#pragma unroll
    for (int mi = 0; mi < 4; ++mi)
#pragma unroll
      for (int reg = 0; reg < 4; ++reg)
        coefp[mi][reg] += __shfl_xor(coefp[mi][reg], mask, 64);
  if (r == 0) {
#pragma unroll
    for (int mi = 0; mi < 4; ++mi)
#pragma unroll
      for (int reg = 0; reg < 4; ++reg)
        sCoef[w][mi * 16 + q * 4 + reg] = coefp[mi][reg];
  }
  __syncthreads();
  if (t < 64) {
    float cf = sCoef[0][t] + sCoef[1][t] + sCoef[2][t] + sCoef[3][t];
    int dn = sDst[t];
#pragma unroll
    for (int c = 0; c < 3; ++c)
      atomicAdd(posdelta + dn * 3 + c, sDv[c][t] * cf);
  }
}

// ---------------- MFMA node-update kernel ----------------
// h[m] += relu([hbf[m] | agg[m]] @ Wut + bu), 64 rows per block.
__launch_bounds__(256)
__global__ void upd_mfma(float* __restrict__ h, const unsigned short* __restrict__ hbf,
                         const float* __restrict__ agg,
                         const unsigned short* __restrict__ Wt,   // [8][256][64] bf16
                         const float* __restrict__ bu) {
  __shared__ __align__(16) unsigned short sW[256 * 72];
  __shared__ __align__(16) unsigned short sA[64 * 72];

  const int t = threadIdx.x;
  const int m0 = blockIdx.x << 6;
  const int w = t >> 6;
  const int lane = t & 63;
  const int q = lane >> 4;
  const int r = lane & 15;
  const int eA = t >> 2;
  const int jA = t & 3;

  f32x4 acc[4][4];
#pragma unroll
  for (int mi = 0; mi < 4; ++mi)
#pragma unroll
    for (int ni = 0; ni < 4; ++ni)
      acc[mi][ni] = (f32x4){0.f, 0.f, 0.f, 0.f};

  for (int kc = 0; kc < 8; ++kc) {
    unsigned short* dstp = sA + eA * 72 + (jA << 4);
    if (kc < 4) {
      const unsigned short* src = hbf + (((size_t)(m0 + eA)) << 8) + (kc << 6) + (jA << 4);
      *(short8*)(dstp) = *(const short8*)(src);
      *(short8*)(dstp + 8) = *(const short8*)(src + 8);
    } else {
      const float* src = agg + (((size_t)(m0 + eA)) << 8) + ((kc - 4) << 6) + (jA << 4);
      const float4 a = *(const float4*)(src);
      const float4 b = *(const float4*)(src + 4);
      const float4 c = *(const float4*)(src + 8);
      const float4 d = *(const float4*)(src + 12);
      short8 v0, v1;
      v0[0] = (short)f2bf(a.x); v0[1] = (short)f2bf(a.y); v0[2] = (short)f2bf(a.z); v0[3] = (short)f2bf(a.w);
      v0[4] = (short)f2bf(b.x); v0[5] = (short)f2bf(b.y); v0[6] = (short)f2bf(b.z); v0[7] = (short)f2bf(b.w);
      v1[0] = (short)f2bf(c.x); v1[1] = (short)f2bf(c.y); v1[2] = (short)f2bf(c.z); v1[3] = (short)f2bf(c.w);
      v1[4] = (short)f2bf(d.x); v1[5] = (short)f2bf(d.y); v1[6] = (short)f2bf(d.z); v1[7] = (short)f2bf(d.w);
      *(short8*)(dstp) = v0;
      *(short8*)(dstp + 8) = v1;
    }
    {
      const unsigned short* src = Wt + (((size_t)kc) << 14) + (t << 3);
      const int nb = t >> 3;
      const int kb = (t & 7) << 3;
#pragma unroll
      for (int i = 0; i < 8; ++i) {
        short8 v = *(const short8*)(src + (i << 11));
        *(short8*)(sW + ((i << 5) + nb) * 72 + kb) = v;
      }
    }
    __syncthreads();
#pragma unroll
    for (int ks = 0; ks < 2; ++ks) {
      const int ko = (ks << 5) + (q << 3);
      short8 af[4], bfr[4];
#pragma unroll
      for (int mi = 0; mi < 4; ++mi)
        af[mi] = *(const short8*)(sA + (mi * 16 + r) * 72 + ko);
#pragma unroll
      for (int ni = 0; ni < 4; ++ni)
        bfr[ni] = *(const short8*)(sW + ((w << 6) + ni * 16 + r) * 72 + ko);
#pragma unroll
      for (int mi = 0; mi < 4; ++mi)
#pragma unroll
        for (int ni = 0; ni < 4; ++ni)
          acc[mi][ni] = __builtin_amdgcn_mfma_f32_16x16x32_bf16(af[mi], bfr[ni], acc[mi][ni], 0, 0, 0);
    }
    __syncthreads();
  }

#pragma unroll
  for (int ni = 0; ni < 4; ++ni) {
    int n = (w << 6) + ni * 16 + r;
    float buv = bu[n];
#pragma unroll
    for (int mi = 0; mi < 4; ++mi)
#pragma unroll
      for (int reg = 0; reg < 4; ++reg) {
        int m = m0 + mi * 16 + q * 4 + reg;
        float* hp = h + (((size_t)m) << 8) + n;
        *hp += fmaxf(acc[mi][ni][reg] + buv, 0.f);
      }
  }
}

// ---------------- launcher ----------------

extern "C" void kernel_launch(void* const* d_in, const int* in_sizes, int n_in,
                              void* d_out, int out_size, void* d_ws, size_t ws_size,
                              hipStream_t stream) {
  const float* x         = (const float*)d_in[0];
  const float* positions = (const float*)d_in[1];
  const float* W_in      = (const float*)d_in[2];
  const float* b_in      = (const float*)d_in[3];
  const float* Wg1       = (const float*)d_in[4];
  const float* bg1       = (const float*)d_in[5];
  const float* Wg2       = (const float*)d_in[6];
  const float* bg2       = (const float*)d_in[7];
  const float* Wm        = (const float*)d_in[8];
  const float* bm        = (const float*)d_in[9];
  const float* Wu        = (const float*)d_in[10];
  const float* bu        = (const float*)d_in[11];
  const float* Wp        = (const float*)d_in[12];
  const float* W_out     = (const float*)d_in[13];
  const float* b_out     = (const float*)d_in[14];
  const int*   ei        = (const int*)d_in[15];
  float* out = (float*)d_out;

  char* ws = (char*)d_ws;
  float*          h    = (float*)(ws);                              // 64 MB
  float*          agg  = (float*)(ws + 67108864UL);                 // 64 MB
  unsigned short* hbf  = (unsigned short*)(ws + 134217728UL);       // 32 MB
  float*          pos  = (float*)(ws + 167772160UL);                // 768 KB
  float*          pd   = (float*)(ws + 168558592UL);                // 768 KB
  float*          g    = (float*)(ws + 169345024UL);                // 2 MB
  float*          h0   = (float*)(ws + 171442176UL);                // 32 KB
  float*          md   = (float*)(ws + 171474944UL);                // 8 KB
  unsigned short* Wmt  = (unsigned short*)(ws + 171483136UL);       // 2 x 256 KB
  unsigned short* Wut  = (unsigned short*)(ws + 172007424UL);       // 2 x 256 KB

  // one-time weight conversions (per call; cheap)
  for (int l = 0; l < L_; ++l) {
    wconv_kernel<<<512, 256, 0, stream>>>(Wm + (size_t)l * 513 * H_, Wmt + (size_t)l * 131072);
    wconv_kernel<<<512, 256, 0, stream>>>(Wu + (size_t)l * 512 * H_, Wut + (size_t)l * 131072);
  }

  h0_kernel<<<B_, 256, 0, stream>>>(x, W_in, b_in, h0);
  meand_kernel<<<N_, 256, 0, stream>>>(positions, md);
  g_kernel<<<N_, 256, 0, stream>>>(md, Wg1, bg1, Wg2, bg2, g);
  hinit_kernel<<<NN_ * 64 / 256, 256, 0, stream>>>(h0, g, h);
  posinit_kernel<<<NN_ * 3 / 256, 256, 0, stream>>>(positions, pos);

  for (int l = 0; l < L_; ++l) {
    hbf_kernel<<<NN_ * H_ / 8 / 256, 256, 0, stream>>>(h, hbf);
    hipMemsetAsync(agg, 0, (size_t)NN_ * H_ * sizeof(float), stream);
    hipMemsetAsync(pd, 0, (size_t)NN_ * 3 * sizeof(float), stream);
    msg_mfma<<<E_ / 64, 256, 0, stream>>>(hbf, pos, ei,
                                          Wmt + (size_t)l * 131072,
                                          Wm + (size_t)l * 513 * H_ + 512 * H_,  // distance row fp32
                                          bm + (size_t)l * H_,
                                          Wp + (size_t)l * H_,
                                          agg, pd);
    posupd_kernel<<<NN_ * 3 / 256, 256, 0, stream>>>(pos, pd);
    upd_mfma<<<NN_ / 64, 256, 0, stream>>>(h, hbf, agg, Wut + (size_t)l * 131072, bu + (size_t)l * H_);
  }

  out_kernel<<<NN_ * 64 / 256, 256, 0, stream>>>(h, W_out, b_out, out);
}

// Round 3
// 658.374 us; speedup vs baseline: 4.2790x; 1.2861x over previous
//
#include <hip/hip_runtime.h>
#include <math.h>

#define B_ 32
#define F_ 128
#define H_ 256
#define N_ 2048
#define L_ 2
#define E_ 262144
#define NN_ 65536          // B_*N_
// DEG = E/(B*N) = 4

typedef __attribute__((ext_vector_type(8))) short short8;   // 8 bf16 = 4 VGPRs (MFMA A/B frag)
typedef __attribute__((ext_vector_type(4))) float f32x4;    // MFMA C/D frag

static __device__ __forceinline__ unsigned short f2bf(float f) {
  unsigned int u = __float_as_uint(f);
  u += 0x7FFF + ((u >> 16) & 1);      // round-to-nearest-even
  return (unsigned short)(u >> 16);
}
static __device__ __forceinline__ float bf2f(unsigned short u) {
  return __uint_as_float(((unsigned int)u) << 16);
}

// ---------------- small kernels ----------------

__global__ void h0_kernel(const float* __restrict__ x, const float* __restrict__ W_in,
                          const float* __restrict__ b_in, float* __restrict__ h0) {
  int b = blockIdx.x;
  int j = threadIdx.x;
  float acc = b_in[j];
#pragma unroll 8
  for (int k = 0; k < F_; ++k)
    acc += x[b * F_ + k] * W_in[k * H_ + j];
  h0[b * H_ + j] = acc;
}

__global__ void meand_kernel(const float* __restrict__ positions, float* __restrict__ mean_d) {
  __shared__ float red[256];
  int i = blockIdx.x;
  int t = threadIdx.x;
  float px = positions[i * 3 + 0], py = positions[i * 3 + 1], pz = positions[i * 3 + 2];
  float s = 0.f;
  for (int j = t; j < N_; j += 256) {
    float dx = px - positions[j * 3 + 0];
    float dy = py - positions[j * 3 + 1];
    float dz = pz - positions[j * 3 + 2];
    s += sqrtf(dx * dx + dy * dy + dz * dz);
  }
  red[t] = s;
  __syncthreads();
  for (int off = 128; off > 0; off >>= 1) {
    if (t < off) red[t] += red[t + off];
    __syncthreads();
  }
  if (t == 0) mean_d[i] = red[0] / (float)(N_ - 1);
}

__global__ void g_kernel(const float* __restrict__ mean_d,
                         const float* __restrict__ Wg1, const float* __restrict__ bg1,
                         const float* __restrict__ Wg2, const float* __restrict__ bg2,
                         float* __restrict__ g) {
  __shared__ float hid[128];
  int n = blockIdx.x;
  int t = threadIdx.x;
  float md = mean_d[n];
  if (t < 128) {
    float w = Wg1[t] + Wg1[128 + t] + Wg1[256 + t];
    hid[t] = fmaxf(md * w + bg1[t], 0.f);
  }
  __syncthreads();
  float acc = bg2[t];
#pragma unroll 8
  for (int k = 0; k < 128; ++k)
    acc += hid[k] * Wg2[k * H_ + t];
  g[n * H_ + t] = acc;
}

__global__ void hinit_kernel(const float* __restrict__ h0, const float* __restrict__ g,
                             float* __restrict__ h) {
  int idx = blockIdx.x * blockDim.x + threadIdx.x;
  int row = idx >> 6;
  int c4 = (idx & 63) << 2;
  const float4 a = *(const float4*)(h0 + (row >> 11) * H_ + c4);
  const float4 b = *(const float4*)(g + (row & (N_ - 1)) * H_ + c4);
  float4 r;
  r.x = a.x + b.x; r.y = a.y + b.y; r.z = a.z + b.z; r.w = a.w + b.w;
  *(float4*)(h + row * H_ + c4) = r;
}

__global__ void posinit_kernel(const float* __restrict__ positions, float* __restrict__ pos) {
  int i = blockIdx.x * blockDim.x + threadIdx.x;
  int row = i / 3;
  int c = i - row * 3;
  pos[i] = positions[(row & (N_ - 1)) * 3 + c];
}

__global__ void posupd_kernel(float* __restrict__ pos, const float* __restrict__ pd) {
  int i = blockIdx.x * blockDim.x + threadIdx.x;
  pos[i] += pd[i] * 0.25f;
}

__global__ void out_kernel(const float* __restrict__ h, const float* __restrict__ Wout,
                           const float* __restrict__ bout, float* __restrict__ out) {
  int gid = blockIdx.x * blockDim.x + threadIdx.x;
  int node = gid >> 6;
  int lane = gid & 63;
  const float4 hv = *(const float4*)(h + node * H_ + (lane << 2));
  const float4 wv = *(const float4*)(Wout + (lane << 2));
  float p = hv.x * wv.x + hv.y * wv.y + hv.z * wv.z + hv.w * wv.w;
#pragma unroll
  for (int m = 1; m < 64; m <<= 1) p += __shfl_xor(p, m, 64);
  if (lane == 0) out[node] = p + bout[0];
}

// ---------------- CSR build (counting sort of edges by dst) ----------------

__global__ void deg_kernel(const int* __restrict__ ei, int* __restrict__ deg) {
  int e = blockIdx.x * 256 + threadIdx.x;
  atomicAdd(&deg[ei[E_ + e]], 1);
}

// per-chunk totals: 256 blocks x 256 threads over 65536 nodes
__global__ void scan1_kernel(const int* __restrict__ deg, int* __restrict__ bsum) {
  __shared__ int red[256];
  int t = threadIdx.x;
  red[t] = deg[blockIdx.x * 256 + t];
  __syncthreads();
  for (int off = 128; off > 0; off >>= 1) {
    if (t < off) red[t] += red[t + off];
    __syncthreads();
  }
  if (t == 0) bsum[blockIdx.x] = red[0];
}

// single-block exclusive scan of the 256 chunk totals (in place)
__global__ void scan2_kernel(int* __restrict__ bsum) {
  __shared__ int s[256];
  int t = threadIdx.x;
  s[t] = bsum[t];
  __syncthreads();
  for (int off = 1; off < 256; off <<= 1) {
    int v = (t >= off) ? s[t - off] : 0;
    __syncthreads();
    s[t] += v;
    __syncthreads();
  }
  bsum[t] = (t == 0) ? 0 : s[t - 1];
}

// per-chunk exclusive scan + chunk base -> cursor array
__global__ void scan3_kernel(const int* __restrict__ deg, const int* __restrict__ bsum,
                             int* __restrict__ cur) {
  __shared__ int s[256];
  int t = threadIdx.x;
  int i = blockIdx.x * 256 + t;
  s[t] = deg[i];
  __syncthreads();
  for (int off = 1; off < 256; off <<= 1) {
    int v = (t >= off) ? s[t - off] : 0;
    __syncthreads();
    s[t] += v;
    __syncthreads();
  }
  int excl = (t == 0) ? 0 : s[t - 1];
  cur[i] = bsum[blockIdx.x] + excl;
}

// scatter edges into dst-sorted order
__global__ void scatter_kernel(const int* __restrict__ ei, int* __restrict__ cur,
                               int* __restrict__ src_s, int* __restrict__ dst_s) {
  int e = blockIdx.x * 256 + threadIdx.x;
  int s = ei[e], d = ei[E_ + e];
  int p = atomicAdd(&cur[d], 1);
  src_s[p] = s;
  dst_s[p] = d;
}

// ---------------- bf16 conversion kernels ----------------

// W [512][256] fp32 row-major -> Wt chunk-major [8][256][64] bf16
__global__ void wconv_kernel(const float* __restrict__ W, unsigned short* __restrict__ Wt) {
  int idx = blockIdx.x * blockDim.x + threadIdx.x;   // 131072
  int kc = idx >> 14;
  int rem = idx & 16383;
  int n = rem >> 6;
  int kl = rem & 63;
  Wt[idx] = f2bf(W[(kc * 64 + kl) * H_ + n]);
}

__global__ void hbf_kernel(const float* __restrict__ h, unsigned short* __restrict__ hbf) {
  int i = (blockIdx.x * blockDim.x + threadIdx.x) << 3;
  const float4 a = *(const float4*)(h + i);
  const float4 b = *(const float4*)(h + i + 4);
  short8 v;
  v[0] = (short)f2bf(a.x); v[1] = (short)f2bf(a.y);
  v[2] = (short)f2bf(a.z); v[3] = (short)f2bf(a.w);
  v[4] = (short)f2bf(b.x); v[5] = (short)f2bf(b.y);
  v[6] = (short)f2bf(b.z); v[7] = (short)f2bf(b.w);
  *(short8*)(hbf + i) = v;
}

// ---------------- MFMA message kernel (dst-sorted edges) ----------------
// Block tile: 64 dst-sorted edges x 256 channels, K=512 in 8 chunks of 64.
// Epilogue: relu'd m-tile -> LDS (bf16, union with W tile), segmented column
// sum over dst-runs, ONE coalesced fp32 atomic per (segment, channel).
__launch_bounds__(256)
__global__ void msg_mfma(const unsigned short* __restrict__ hbf,
                         const float* __restrict__ pos,
                         const int* __restrict__ src_s, const int* __restrict__ dst_s,
                         const unsigned short* __restrict__ Wt,   // [8][256][64] bf16
                         const float* __restrict__ wl,            // Wm row 512 fp32 [256]
                         const float* __restrict__ bm,
                         const float* __restrict__ Wp,
                         float* __restrict__ agg, float* __restrict__ posdelta) {
  // sM stride 268 shorts: write pattern lands q-groups on distinct bank octets
  __shared__ __align__(16) union {
    unsigned short W[256 * 72];   // [n][kl] during K-loop
    unsigned short M[64 * 268];   // [edge][ch] bf16 m-tile during epilogue
  } sU;
  __shared__ __align__(16) unsigned short sA[64 * 72];
  __shared__ float sCoef[4][64];
  __shared__ float sD[64];
  __shared__ float sDv[3][64];
  __shared__ int sSrc[64];
  __shared__ int sDst[64];
  __shared__ unsigned long long sMask;

  const int t = threadIdx.x;
  const int e0 = blockIdx.x << 6;

  if (t < 64) {
    int s = src_s[e0 + t], d = dst_s[e0 + t];
    sSrc[t] = s; sDst[t] = d;
    float dx = pos[d * 3 + 0] - pos[s * 3 + 0];
    float dy = pos[d * 3 + 1] - pos[s * 3 + 1];
    float dz = pos[d * 3 + 2] - pos[s * 3 + 2];
    sDv[0][t] = dx; sDv[1][t] = dy; sDv[2][t] = dz;
    sD[t] = sqrtf(dx * dx + dy * dy + dz * dz + 1e-12f);
  }
  __syncthreads();
  if (t == 0) {
    unsigned long long m = 1ull;   // segment-start mask over the 64 sorted edges
    for (int e = 1; e < 64; ++e)
      if (sDst[e] != sDst[e - 1]) m |= (1ull << e);
    sMask = m;   // visible after the K-loop barriers
  }

  const int w = t >> 6;
  const int lane = t & 63;
  const int q = lane >> 4;
  const int r = lane & 15;
  const int eA = t >> 2;
  const int jA = t & 3;

  f32x4 acc[4][4];
#pragma unroll
  for (int mi = 0; mi < 4; ++mi)
#pragma unroll
    for (int ni = 0; ni < 4; ++ni)
      acc[mi][ni] = (f32x4){0.f, 0.f, 0.f, 0.f};

  const int rsrc = sSrc[eA];
  const int rdst = sDst[eA];   // sorted: near-sequential across blocks

  for (int kc = 0; kc < 8; ++kc) {
    {
      int row = (kc < 4) ? rsrc : rdst;
      int cb = ((kc & 3) << 6) + (jA << 4);
      const unsigned short* src = hbf + (((size_t)row) << 8) + cb;
      short8 v0 = *(const short8*)(src);
      short8 v1 = *(const short8*)(src + 8);
      unsigned short* dst = sA + eA * 72 + (jA << 4);
      *(short8*)(dst) = v0;
      *(short8*)(dst + 8) = v1;
    }
    {
      const unsigned short* src = Wt + (((size_t)kc) << 14) + (t << 3);
      const int nb = t >> 3;
      const int kb = (t & 7) << 3;
#pragma unroll
      for (int i = 0; i < 8; ++i) {
        short8 v = *(const short8*)(src + (i << 11));
        *(short8*)(sU.W + ((i << 5) + nb) * 72 + kb) = v;
      }
    }
    __syncthreads();
#pragma unroll
    for (int ks = 0; ks < 2; ++ks) {
      const int ko = (ks << 5) + (q << 3);
      short8 af[4], bfr[4];
#pragma unroll
      for (int mi = 0; mi < 4; ++mi)
        af[mi] = *(const short8*)(sA + (mi * 16 + r) * 72 + ko);
#pragma unroll
      for (int ni = 0; ni < 4; ++ni)
        bfr[ni] = *(const short8*)(sU.W + ((w << 6) + ni * 16 + r) * 72 + ko);
#pragma unroll
      for (int mi = 0; mi < 4; ++mi)
#pragma unroll
        for (int ni = 0; ni < 4; ++ni)
          acc[mi][ni] = __builtin_amdgcn_mfma_f32_16x16x32_bf16(af[mi], bfr[ni], acc[mi][ni], 0, 0, 0);
    }
    __syncthreads();
  }
  // all waves past final barrier: sU.W dead, sU.M live

  float wlv[4], bmv[4], wpv[4];
#pragma unroll
  for (int ni = 0; ni < 4; ++ni) {
    int n = (w << 6) + ni * 16 + r;
    wlv[ni] = wl[n]; bmv[ni] = bm[n]; wpv[ni] = Wp[n];
  }
  float coefp[4][4];
#pragma unroll
  for (int mi = 0; mi < 4; ++mi)
#pragma unroll
    for (int reg = 0; reg < 4; ++reg)
      coefp[mi][reg] = 0.f;

#pragma unroll
  for (int mi = 0; mi < 4; ++mi) {
#pragma unroll
    for (int reg = 0; reg < 4; ++reg) {
      int m = mi * 16 + q * 4 + reg;     // edge row (C layout: row = quad*4+reg)
      float dv = sD[m];
#pragma unroll
      for (int ni = 0; ni < 4; ++ni) {
        float v = acc[mi][ni][reg] + dv * wlv[ni] + bmv[ni];
        v = fmaxf(v, 0.f);
        coefp[mi][reg] += v * wpv[ni];
        sU.M[m * 268 + ((w << 6) + ni * 16 + r)] = f2bf(v);
      }
    }
  }
  // coef: reduce over the 16 r-lanes (same q share the same edge rows)
#pragma unroll
  for (int mask = 1; mask < 16; mask <<= 1)
#pragma unroll
    for (int mi = 0; mi < 4; ++mi)
#pragma unroll
      for (int reg = 0; reg < 4; ++reg)
        coefp[mi][reg] += __shfl_xor(coefp[mi][reg], mask, 64);
  if (r == 0) {
#pragma unroll
    for (int mi = 0; mi < 4; ++mi)
#pragma unroll
      for (int reg = 0; reg < 4; ++reg)
        sCoef[w][mi * 16 + q * 4 + reg] = coefp[mi][reg];
  }
  __syncthreads();

  // segmented column sum: thread t owns channel t; one coalesced atomic per segment
  {
    const unsigned long long mask = sMask;
    int seg = 0;
    while (seg < 64) {
      unsigned long long rest = (seg < 63) ? ((mask >> (seg + 1)) << (seg + 1)) : 0ull;
      int segend = rest ? (__ffsll((long long)rest) - 1) : 64;
      float sum = 0.f;
      for (int e = seg; e < segend; ++e)
        sum += bf2f(sU.M[e * 268 + t]);
      atomicAdd(agg + (((size_t)sDst[seg]) << 8) + t, sum);
      seg = segend;
    }
  }
  // posdelta: one atomic triple per segment
  if (t < 64 && ((sMask >> t) & 1ull)) {
    unsigned long long rest = (t < 63) ? ((sMask >> (t + 1)) << (t + 1)) : 0ull;
    int segend = rest ? (__ffsll((long long)rest) - 1) : 64;
    float cx = 0.f, cy = 0.f, cz = 0.f;
    for (int e = t; e < segend; ++e) {
      float cf = sCoef[0][e] + sCoef[1][e] + sCoef[2][e] + sCoef[3][e];
      cx += sDv[0][e] * cf; cy += sDv[1][e] * cf; cz += sDv[2][e] * cf;
    }
    int dn = sDst[t];
    atomicAdd(posdelta + dn * 3 + 0, cx);
    atomicAdd(posdelta + dn * 3 + 1, cy);
    atomicAdd(posdelta + dn * 3 + 2, cz);
  }
}

// ---------------- MFMA node-update kernel ----------------
__launch_bounds__(256)
__global__ void upd_mfma(float* __restrict__ h, const unsigned short* __restrict__ hbf,
                         const float* __restrict__ agg,
                         const unsigned short* __restrict__ Wt,   // [8][256][64] bf16
                         const float* __restrict__ bu) {
  __shared__ __align__(16) unsigned short sW[256 * 72];
  __shared__ __align__(16) unsigned short sA[64 * 72];

  const int t = threadIdx.x;
  const int m0 = blockIdx.x << 6;
  const int w = t >> 6;
  const int lane = t & 63;
  const int q = lane >> 4;
  const int r = lane & 15;
  const int eA = t >> 2;
  const int jA = t & 3;

  f32x4 acc[4][4];
#pragma unroll
  for (int mi = 0; mi < 4; ++mi)
#pragma unroll
    for (int ni = 0; ni < 4; ++ni)
      acc[mi][ni] = (f32x4){0.f, 0.f, 0.f, 0.f};

  for (int kc = 0; kc < 8; ++kc) {
    unsigned short* dstp = sA + eA * 72 + (jA << 4);
    if (kc < 4) {
      const unsigned short* src = hbf + (((size_t)(m0 + eA)) << 8) + (kc << 6) + (jA << 4);
      *(short8*)(dstp) = *(const short8*)(src);
      *(short8*)(dstp + 8) = *(const short8*)(src + 8);
    } else {
      const float* src = agg + (((size_t)(m0 + eA)) << 8) + ((kc - 4) << 6) + (jA << 4);
      const float4 a = *(const float4*)(src);
      const float4 b = *(const float4*)(src + 4);
      const float4 c = *(const float4*)(src + 8);
      const float4 d = *(const float4*)(src + 12);
      short8 v0, v1;
      v0[0] = (short)f2bf(a.x); v0[1] = (short)f2bf(a.y); v0[2] = (short)f2bf(a.z); v0[3] = (short)f2bf(a.w);
      v0[4] = (short)f2bf(b.x); v0[5] = (short)f2bf(b.y); v0[6] = (short)f2bf(b.z); v0[7] = (short)f2bf(b.w);
      v1[0] = (short)f2bf(c.x); v1[1] = (short)f2bf(c.y); v1[2] = (short)f2bf(c.z); v1[3] = (short)f2bf(c.w);
      v1[4] = (short)f2bf(d.x); v1[5] = (short)f2bf(d.y); v1[6] = (short)f2bf(d.z); v1[7] = (short)f2bf(d.w);
      *(short8*)(dstp) = v0;
      *(short8*)(dstp + 8) = v1;
    }
    {
      const unsigned short* src = Wt + (((size_t)kc) << 14) + (t << 3);
      const int nb = t >> 3;
      const int kb = (t & 7) << 3;
#pragma unroll
      for (int i = 0; i < 8; ++i) {
        short8 v = *(const short8*)(src + (i << 11));
        *(short8*)(sW + ((i << 5) + nb) * 72 + kb) = v;
      }
    }
    __syncthreads();
#pragma unroll
    for (int ks = 0; ks < 2; ++ks) {
      const int ko = (ks << 5) + (q << 3);
      short8 af[4], bfr[4];
#pragma unroll
      for (int mi = 0; mi < 4; ++mi)
        af[mi] = *(const short8*)(sA + (mi * 16 + r) * 72 + ko);
#pragma unroll
      for (int ni = 0; ni < 4; ++ni)
        bfr[ni] = *(const short8*)(sW + ((w << 6) + ni * 16 + r) * 72 + ko);
#pragma unroll
      for (int mi = 0; mi < 4; ++mi)
#pragma unroll
        for (int ni = 0; ni < 4; ++ni)
          acc[mi][ni] = __builtin_amdgcn_mfma_f32_16x16x32_bf16(af[mi], bfr[ni], acc[mi][ni], 0, 0, 0);
    }
    __syncthreads();
  }

#pragma unroll
  for (int ni = 0; ni < 4; ++ni) {
    int n = (w << 6) + ni * 16 + r;
    float buv = bu[n];
#pragma unroll
    for (int mi = 0; mi < 4; ++mi)
#pragma unroll
      for (int reg = 0; reg < 4; ++reg) {
        int m = m0 + mi * 16 + q * 4 + reg;
        float* hp = h + (((size_t)m) << 8) + n;
        *hp += fmaxf(acc[mi][ni][reg] + buv, 0.f);
      }
  }
}

// ---------------- launcher ----------------

extern "C" void kernel_launch(void* const* d_in, const int* in_sizes, int n_in,
                              void* d_out, int out_size, void* d_ws, size_t ws_size,
                              hipStream_t stream) {
  const float* x         = (const float*)d_in[0];
  const float* positions = (const float*)d_in[1];
  const float* W_in      = (const float*)d_in[2];
  const float* b_in      = (const float*)d_in[3];
  const float* Wg1       = (const float*)d_in[4];
  const float* bg1       = (const float*)d_in[5];
  const float* Wg2       = (const float*)d_in[6];
  const float* bg2       = (const float*)d_in[7];
  const float* Wm        = (const float*)d_in[8];
  const float* bm        = (const float*)d_in[9];
  const float* Wu        = (const float*)d_in[10];
  const float* bu        = (const float*)d_in[11];
  const float* Wp        = (const float*)d_in[12];
  const float* W_out     = (const float*)d_in[13];
  const float* b_out     = (const float*)d_in[14];
  const int*   ei        = (const int*)d_in[15];
  float* out = (float*)d_out;

  char* ws = (char*)d_ws;
  float*          h     = (float*)(ws);                          // 64 MB
  float*          agg   = (float*)(ws + 67108864UL);             // 64 MB
  unsigned short* hbf   = (unsigned short*)(ws + 134217728UL);   // 32 MB
  float*          pos   = (float*)(ws + 167772160UL);            // 768 KB
  float*          pd    = (float*)(ws + 168558592UL);            // 768 KB
  float*          g     = (float*)(ws + 169345024UL);            // 2 MB
  float*          h0    = (float*)(ws + 171442176UL);            // 32 KB
  float*          md    = (float*)(ws + 171474944UL);            // 8 KB
  unsigned short* Wmt   = (unsigned short*)(ws + 171483136UL);   // 512 KB
  unsigned short* Wut   = (unsigned short*)(ws + 172007424UL);   // 512 KB
  int*            deg   = (int*)(ws + 172531712UL);              // 256 KB
  int*            cur   = (int*)(ws + 172793856UL);              // 256 KB
  int*            bsum  = (int*)(ws + 173056000UL);              // 1 KB
  int*            src_s = (int*)(ws + 173057024UL);              // 1 MB
  int*            dst_s = (int*)(ws + 174105600UL);              // 1 MB

  // ---- CSR permutation (counting sort by dst), once per call ----
  hipMemsetAsync(deg, 0, (size_t)NN_ * sizeof(int), stream);
  deg_kernel<<<E_ / 256, 256, 0, stream>>>(ei, deg);
  scan1_kernel<<<256, 256, 0, stream>>>(deg, bsum);
  scan2_kernel<<<1, 256, 0, stream>>>(bsum);
  scan3_kernel<<<256, 256, 0, stream>>>(deg, bsum, cur);
  scatter_kernel<<<E_ / 256, 256, 0, stream>>>(ei, cur, src_s, dst_s);

  // ---- weight conversion + node init ----
  for (int l = 0; l < L_; ++l) {
    wconv_kernel<<<512, 256, 0, stream>>>(Wm + (size_t)l * 513 * H_, Wmt + (size_t)l * 131072);
    wconv_kernel<<<512, 256, 0, stream>>>(Wu + (size_t)l * 512 * H_, Wut + (size_t)l * 131072);
  }
  h0_kernel<<<B_, 256, 0, stream>>>(x, W_in, b_in, h0);
  meand_kernel<<<N_, 256, 0, stream>>>(positions, md);
  g_kernel<<<N_, 256, 0, stream>>>(md, Wg1, bg1, Wg2, bg2, g);
  hinit_kernel<<<NN_ * 64 / 256, 256, 0, stream>>>(h0, g, h);
  posinit_kernel<<<NN_ * 3 / 256, 256, 0, stream>>>(positions, pos);

  for (int l = 0; l < L_; ++l) {
    hbf_kernel<<<NN_ * H_ / 8 / 256, 256, 0, stream>>>(h, hbf);
    hipMemsetAsync(agg, 0, (size_t)NN_ * H_ * sizeof(float), stream);
    hipMemsetAsync(pd, 0, (size_t)NN_ * 3 * sizeof(float), stream);
    msg_mfma<<<E_ / 64, 256, 0, stream>>>(hbf, pos, src_s, dst_s,
                                          Wmt + (size_t)l * 131072,
                                          Wm + (size_t)l * 513 * H_ + 512 * H_,
                                          bm + (size_t)l * H_,
                                          Wp + (size_t)l * H_,
                                          agg, pd);
    posupd_kernel<<<NN_ * 3 / 256, 256, 0, stream>>>(pos, pd);
    upd_mfma<<<NN_ / 64, 256, 0, stream>>>(h, hbf, agg, Wut + (size_t)l * 131072, bu + (size_t)l * H_);
  }

  out_kernel<<<NN_ * 64 / 256, 256, 0, stream>>>(h, W_out, b_out, out);
}

// Round 5
// 538.107 us; speedup vs baseline: 5.2353x; 1.2235x over previous
//
#include <hip/hip_runtime.h>
#include <math.h>

#define B_ 32
#define F_ 128
#define H_ 256
#define N_ 2048
#define L_ 2
#define E_ 262144
#define NN_ 65536          // B_*N_
// DEG = E/(B*N) = 4

typedef __attribute__((ext_vector_type(8))) short short8;   // 8 bf16 = 4 VGPRs (MFMA A/B frag)
typedef __attribute__((ext_vector_type(4))) float f32x4;    // MFMA C/D frag

static __device__ __forceinline__ unsigned short f2bf(float f) {
  unsigned int u = __float_as_uint(f);
  u += 0x7FFF + ((u >> 16) & 1);      // round-to-nearest-even
  return (unsigned short)(u >> 16);
}
static __device__ __forceinline__ float bf2f(unsigned short u) {
  return __uint_as_float(((unsigned int)u) << 16);
}

// ---------------- small kernels ----------------

__global__ void h0_kernel(const float* __restrict__ x, const float* __restrict__ W_in,
                          const float* __restrict__ b_in, float* __restrict__ h0) {
  int b = blockIdx.x;
  int j = threadIdx.x;
  float acc = b_in[j];
#pragma unroll 8
  for (int k = 0; k < F_; ++k)
    acc += x[b * F_ + k] * W_in[k * H_ + j];
  h0[b * H_ + j] = acc;
}

__global__ void meand_kernel(const float* __restrict__ positions, float* __restrict__ mean_d) {
  __shared__ float red[256];
  int i = blockIdx.x;
  int t = threadIdx.x;
  float px = positions[i * 3 + 0], py = positions[i * 3 + 1], pz = positions[i * 3 + 2];
  float s = 0.f;
  for (int j = t; j < N_; j += 256) {
    float dx = px - positions[j * 3 + 0];
    float dy = py - positions[j * 3 + 1];
    float dz = pz - positions[j * 3 + 2];
    s += sqrtf(dx * dx + dy * dy + dz * dz);
  }
  red[t] = s;
  __syncthreads();
  for (int off = 128; off > 0; off >>= 1) {
    if (t < off) red[t] += red[t + off];
    __syncthreads();
  }
  if (t == 0) mean_d[i] = red[0] / (float)(N_ - 1);
}

__global__ void g_kernel(const float* __restrict__ mean_d,
                         const float* __restrict__ Wg1, const float* __restrict__ bg1,
                         const float* __restrict__ Wg2, const float* __restrict__ bg2,
                         float* __restrict__ g) {
  __shared__ float hid[128];
  int n = blockIdx.x;
  int t = threadIdx.x;
  float md = mean_d[n];
  if (t < 128) {
    float w = Wg1[t] + Wg1[128 + t] + Wg1[256 + t];
    hid[t] = fmaxf(md * w + bg1[t], 0.f);
  }
  __syncthreads();
  float acc = bg2[t];
#pragma unroll 8
  for (int k = 0; k < 128; ++k)
    acc += hid[k] * Wg2[k * H_ + t];
  g[n * H_ + t] = acc;
}

__global__ void hinit_kernel(const float* __restrict__ h0, const float* __restrict__ g,
                             float* __restrict__ h) {
  int idx = blockIdx.x * blockDim.x + threadIdx.x;
  int row = idx >> 6;
  int c4 = (idx & 63) << 2;
  const float4 a = *(const float4*)(h0 + (row >> 11) * H_ + c4);
  const float4 b = *(const float4*)(g + (row & (N_ - 1)) * H_ + c4);
  float4 r;
  r.x = a.x + b.x; r.y = a.y + b.y; r.z = a.z + b.z; r.w = a.w + b.w;
  *(float4*)(h + row * H_ + c4) = r;
}

__global__ void posinit_kernel(const float* __restrict__ positions, float* __restrict__ pos) {
  int i = blockIdx.x * blockDim.x + threadIdx.x;
  int row = i / 3;
  int c = i - row * 3;
  pos[i] = positions[(row & (N_ - 1)) * 3 + c];
}

__global__ void out_kernel(const float* __restrict__ h, const float* __restrict__ Wout,
                           const float* __restrict__ bout, float* __restrict__ out) {
  int gid = blockIdx.x * blockDim.x + threadIdx.x;
  int node = gid >> 6;
  int lane = gid & 63;
  const float4 hv = *(const float4*)(h + node * H_ + (lane << 2));
  const float4 wv = *(const float4*)(Wout + (lane << 2));
  float p = hv.x * wv.x + hv.y * wv.y + hv.z * wv.z + hv.w * wv.w;
#pragma unroll
  for (int m = 1; m < 64; m <<= 1) p += __shfl_xor(p, m, 64);
  if (lane == 0) out[node] = p + bout[0];
}

// ---------------- CSR build (counting sort of edges by dst) ----------------

__global__ void deg_kernel(const int* __restrict__ ei, int* __restrict__ deg) {
  int e = blockIdx.x * 256 + threadIdx.x;
  atomicAdd(&deg[ei[E_ + e]], 1);
}

__global__ void scan1_kernel(const int* __restrict__ deg, int* __restrict__ bsum) {
  __shared__ int red[256];
  int t = threadIdx.x;
  red[t] = deg[blockIdx.x * 256 + t];
  __syncthreads();
  for (int off = 128; off > 0; off >>= 1) {
    if (t < off) red[t] += red[t + off];
    __syncthreads();
  }
  if (t == 0) bsum[blockIdx.x] = red[0];
}

__global__ void scan2_kernel(int* __restrict__ bsum) {
  __shared__ int s[256];
  int t = threadIdx.x;
  s[t] = bsum[t];
  __syncthreads();
  for (int off = 1; off < 256; off <<= 1) {
    int v = (t >= off) ? s[t - off] : 0;
    __syncthreads();
    s[t] += v;
    __syncthreads();
  }
  bsum[t] = (t == 0) ? 0 : s[t - 1];
}

__global__ void scan3_kernel(const int* __restrict__ deg, const int* __restrict__ bsum,
                             int* __restrict__ cur) {
  __shared__ int s[256];
  int t = threadIdx.x;
  int i = blockIdx.x * 256 + t;
  s[t] = deg[i];
  __syncthreads();
  for (int off = 1; off < 256; off <<= 1) {
    int v = (t >= off) ? s[t - off] : 0;
    __syncthreads();
    s[t] += v;
    __syncthreads();
  }
  int excl = (t == 0) ? 0 : s[t - 1];
  cur[i] = bsum[blockIdx.x] + excl;
}

// scatter src indices into dst-sorted order
__global__ void scatter_kernel(const int* __restrict__ ei, int* __restrict__ cur,
                               int* __restrict__ src_s) {
  int e = blockIdx.x * 256 + threadIdx.x;
  int s = ei[e], d = ei[E_ + e];
  int p = atomicAdd(&cur[d], 1);
  src_s[p] = s;
}

// ---------------- weight conversion ----------------

// Wm[l] top/bot halves -> Wt1 [2][4][256 n][64 kl] bf16 per layer
__global__ void wconv1_kernel(const float* __restrict__ Wm, unsigned short* __restrict__ Wt) {
  int idx = blockIdx.x * 256 + threadIdx.x;   // 131072
  int g = idx >> 16;
  int rem = idx & 65535;
  int kc = rem >> 14;
  int n = (rem >> 6) & 255;
  int kl = rem & 63;
  Wt[idx] = f2bf(Wm[(g * 256 + kc * 64 + kl) * H_ + n]);
}

// Wu [512][256] fp32 row-major -> [8][256 n][64 kl] bf16
__global__ void wconv_kernel(const float* __restrict__ W, unsigned short* __restrict__ Wt) {
  int idx = blockIdx.x * blockDim.x + threadIdx.x;   // 131072
  int kc = idx >> 14;
  int rem = idx & 16383;
  int n = rem >> 6;
  int kl = rem & 63;
  Wt[idx] = f2bf(W[(kc * 64 + kl) * H_ + n]);
}

__global__ void hbf_kernel(const float* __restrict__ h, unsigned short* __restrict__ hbf) {
  int i = (blockIdx.x * blockDim.x + threadIdx.x) << 3;
  const float4 a = *(const float4*)(h + i);
  const float4 b = *(const float4*)(h + i + 4);
  short8 v;
  v[0] = (short)f2bf(a.x); v[1] = (short)f2bf(a.y);
  v[2] = (short)f2bf(a.z); v[3] = (short)f2bf(a.w);
  v[4] = (short)f2bf(b.x); v[5] = (short)f2bf(b.y);
  v[6] = (short)f2bf(b.z); v[7] = (short)f2bf(b.w);
  *(short8*)(hbf + i) = v;
}

// ---------------- GEMM1: X = hbf@WmTop (bf16), Zb = hbf@WmBot + bm (bf16) ----------------
// grid (NN/64, 2): y=0 -> X, y=1 -> Zb. 64 rows x 256 cols per block, K=256 (4 chunks).
__launch_bounds__(256)
__global__ void gemm1_mfma(const unsigned short* __restrict__ hbf,
                           const unsigned short* __restrict__ Wt,   // [2][4][256][64]
                           const float* __restrict__ bm,
                           unsigned short* __restrict__ X, unsigned short* __restrict__ Zb) {
  __shared__ __align__(16) unsigned short sW[256 * 72];
  __shared__ __align__(16) unsigned short sA[64 * 72];

  const int t = threadIdx.x;
  const int m0 = blockIdx.x << 6;
  const int g = blockIdx.y;
  const int w = t >> 6;
  const int lane = t & 63;
  const int q = lane >> 4;
  const int r = lane & 15;
  const int eA = t >> 2;
  const int jA = t & 3;

  f32x4 acc[4][4];
#pragma unroll
  for (int mi = 0; mi < 4; ++mi)
#pragma unroll
    for (int ni = 0; ni < 4; ++ni)
      acc[mi][ni] = (f32x4){0.f, 0.f, 0.f, 0.f};

  for (int kc = 0; kc < 4; ++kc) {
    {
      const unsigned short* src = hbf + (((size_t)(m0 + eA)) << 8) + (kc << 6) + (jA << 4);
      unsigned short* dstp = sA + eA * 72 + (jA << 4);
      *(short8*)(dstp) = *(const short8*)(src);
      *(short8*)(dstp + 8) = *(const short8*)(src + 8);
    }
    {
      const unsigned short* src = Wt + (((size_t)((g << 2) + kc)) << 14) + (t << 3);
      const int nb = t >> 3;
      const int kb = (t & 7) << 3;
#pragma unroll
      for (int i = 0; i < 8; ++i) {
        short8 v = *(const short8*)(src + (i << 11));
        *(short8*)(sW + ((i << 5) + nb) * 72 + kb) = v;
      }
    }
    __syncthreads();
#pragma unroll
    for (int ks = 0; ks < 2; ++ks) {
      const int ko = (ks << 5) + (q << 3);
      short8 af[4], bfr[4];
#pragma unroll
      for (int mi = 0; mi < 4; ++mi)
        af[mi] = *(const short8*)(sA + (mi * 16 + r) * 72 + ko);
#pragma unroll
      for (int ni = 0; ni < 4; ++ni)
        bfr[ni] = *(const short8*)(sW + ((w << 6) + ni * 16 + r) * 72 + ko);
#pragma unroll
      for (int mi = 0; mi < 4; ++mi)
#pragma unroll
        for (int ni = 0; ni < 4; ++ni)
          acc[mi][ni] = __builtin_amdgcn_mfma_f32_16x16x32_bf16(af[mi], bfr[ni], acc[mi][ni], 0, 0, 0);
    }
    __syncthreads();
  }

#pragma unroll
  for (int ni = 0; ni < 4; ++ni) {
    int n = (w << 6) + ni * 16 + r;
    float bmn = bm[n];
#pragma unroll
    for (int mi = 0; mi < 4; ++mi)
#pragma unroll
      for (int reg = 0; reg < 4; ++reg) {
        size_t idx = (((size_t)(m0 + mi * 16 + q * 4 + reg)) << 8) + n;
        float v = acc[mi][ni][reg];
        if (g == 0) X[idx]  = f2bf(v);
        else        Zb[idx] = f2bf(v + bmn);
      }
  }
}

// ---------------- edge kernel: per-node segment processing, zero atomics ----------------
// m_e = relu(X[src] + Zb[n] + d_e*wl); agg[n] = sum m_e (bf16 out);
// coef_e = m_e@Wp; pos_out[n] = pos[n] + sum((pos[n]-pos[src])*coef_e)/DEG.
// One wave per 8 nodes; lane l owns channels 4l..4l+3.
__launch_bounds__(256)
__global__ void edge_kernel(const unsigned short* __restrict__ X,
                            const unsigned short* __restrict__ Zb,
                            const float* __restrict__ pos_c,
                            const int* __restrict__ rowptr, const int* __restrict__ src_s,
                            const float* __restrict__ wl, const float* __restrict__ wp,
                            unsigned short* __restrict__ aggb, float* __restrict__ pos_o) {
  const int gid = blockIdx.x * 256 + threadIdx.x;
  const int wave = gid >> 6;
  const int lane = threadIdx.x & 63;

  const float4 wlv = *(const float4*)(wl + (lane << 2));
  const float4 wpv = *(const float4*)(wp + (lane << 2));

#pragma unroll 2
  for (int ni = 0; ni < 8; ++ni) {
    const int n = (wave << 3) + ni;
    const int e0 = rowptr[n];
    const int e1 = (n == NN_ - 1) ? E_ : rowptr[n + 1];
    const ushort4 zv = *(const ushort4*)(Zb + (((size_t)n) << 8) + (lane << 2));
    const float z0 = bf2f(zv.x), z1 = bf2f(zv.y), z2 = bf2f(zv.z), z3 = bf2f(zv.w);
    const float pnx = pos_c[n * 3 + 0];
    const float pny = pos_c[n * 3 + 1];
    const float pnz = pos_c[n * 3 + 2];
    float a0 = 0.f, a1 = 0.f, a2 = 0.f, a3 = 0.f;
    float pdx = 0.f, pdy = 0.f, pdz = 0.f;
    for (int e = e0; e < e1; ++e) {
      const int s = src_s[e];
      const float dx = pnx - pos_c[s * 3 + 0];
      const float dy = pny - pos_c[s * 3 + 1];
      const float dz = pnz - pos_c[s * 3 + 2];
      const float d = sqrtf(dx * dx + dy * dy + dz * dz + 1e-12f);
      const ushort4 xv = *(const ushort4*)(X + (((size_t)s) << 8) + (lane << 2));
      const float v0 = fmaxf(bf2f(xv.x) + z0 + d * wlv.x, 0.f);
      const float v1 = fmaxf(bf2f(xv.y) + z1 + d * wlv.y, 0.f);
      const float v2 = fmaxf(bf2f(xv.z) + z2 + d * wlv.z, 0.f);
      const float v3 = fmaxf(bf2f(xv.w) + z3 + d * wlv.w, 0.f);
      a0 += v0; a1 += v1; a2 += v2; a3 += v3;
      float cp = v0 * wpv.x + v1 * wpv.y + v2 * wpv.z + v3 * wpv.w;
#pragma unroll
      for (int m = 1; m < 64; m <<= 1) cp += __shfl_xor(cp, m, 64);
      pdx += dx * cp; pdy += dy * cp; pdz += dz * cp;
    }
    ushort4 av;
    av.x = f2bf(a0); av.y = f2bf(a1); av.z = f2bf(a2); av.w = f2bf(a3);
    *(ushort4*)(aggb + (((size_t)n) << 8) + (lane << 2)) = av;
    if (lane == 0) {
      pos_o[n * 3 + 0] = pnx + pdx * 0.25f;
      pos_o[n * 3 + 1] = pny + pdy * 0.25f;
      pos_o[n * 3 + 2] = pnz + pdz * 0.25f;
    }
  }
}

// ---------------- GEMM2 (node update): h += relu([hbf|aggb]@Wu + bu); hbf = bf16(h) ----------------
__launch_bounds__(256)
__global__ void upd2_mfma(float* __restrict__ h, unsigned short* __restrict__ hbf,
                          const unsigned short* __restrict__ aggb,
                          const unsigned short* __restrict__ Wt,   // [8][256][64] bf16
                          const float* __restrict__ bu) {
  __shared__ __align__(16) unsigned short sW[256 * 72];
  __shared__ __align__(16) unsigned short sA[64 * 72];

  const int t = threadIdx.x;
  const int m0 = blockIdx.x << 6;
  const int w = t >> 6;
  const int lane = t & 63;
  const int q = lane >> 4;
  const int r = lane & 15;
  const int eA = t >> 2;
  const int jA = t & 3;

  f32x4 acc[4][4];
#pragma unroll
  for (int mi = 0; mi < 4; ++mi)
#pragma unroll
    for (int ni = 0; ni < 4; ++ni)
      acc[mi][ni] = (f32x4){0.f, 0.f, 0.f, 0.f};

  for (int kc = 0; kc < 8; ++kc) {
    {
      const unsigned short* base = (kc < 4) ? hbf : aggb;
      const unsigned short* src = base + (((size_t)(m0 + eA)) << 8) + ((kc & 3) << 6) + (jA << 4);
      unsigned short* dstp = sA + eA * 72 + (jA << 4);
      *(short8*)(dstp) = *(const short8*)(src);
      *(short8*)(dstp + 8) = *(const short8*)(src + 8);
    }
    {
      const unsigned short* src = Wt + (((size_t)kc) << 14) + (t << 3);
      const int nb = t >> 3;
      const int kb = (t & 7) << 3;
#pragma unroll
      for (int i = 0; i < 8; ++i) {
        short8 v = *(const short8*)(src + (i << 11));
        *(short8*)(sW + ((i << 5) + nb) * 72 + kb) = v;
      }
    }
    __syncthreads();
#pragma unroll
    for (int ks = 0; ks < 2; ++ks) {
      const int ko = (ks << 5) + (q << 3);
      short8 af[4], bfr[4];
#pragma unroll
      for (int mi = 0; mi < 4; ++mi)
        af[mi] = *(const short8*)(sA + (mi * 16 + r) * 72 + ko);
#pragma unroll
      for (int ni = 0; ni < 4; ++ni)
        bfr[ni] = *(const short8*)(sW + ((w << 6) + ni * 16 + r) * 72 + ko);
#pragma unroll
      for (int mi = 0; mi < 4; ++mi)
#pragma unroll
        for (int ni = 0; ni < 4; ++ni)
          acc[mi][ni] = __builtin_amdgcn_mfma_f32_16x16x32_bf16(af[mi], bfr[ni], acc[mi][ni], 0, 0, 0);
    }
    __syncthreads();
  }

#pragma unroll
  for (int ni = 0; ni < 4; ++ni) {
    int n = (w << 6) + ni * 16 + r;
    float buv = bu[n];
#pragma unroll
    for (int mi = 0; mi < 4; ++mi)
#pragma unroll
      for (int reg = 0; reg < 4; ++reg) {
        size_t idx = (((size_t)(m0 + mi * 16 + q * 4 + reg)) << 8) + n;
        float v = h[idx] + fmaxf(acc[mi][ni][reg] + buv, 0.f);
        h[idx] = v;
        hbf[idx] = f2bf(v);
      }
  }
}

// ---------------- launcher ----------------

extern "C" void kernel_launch(void* const* d_in, const int* in_sizes, int n_in,
                              void* d_out, int out_size, void* d_ws, size_t ws_size,
                              hipStream_t stream) {
  const float* x         = (const float*)d_in[0];
  const float* positions = (const float*)d_in[1];
  const float* W_in      = (const float*)d_in[2];
  const float* b_in      = (const float*)d_in[3];
  const float* Wg1       = (const float*)d_in[4];
  const float* bg1       = (const float*)d_in[5];
  const float* Wg2       = (const float*)d_in[6];
  const float* bg2       = (const float*)d_in[7];
  const float* Wm        = (const float*)d_in[8];
  const float* bm        = (const float*)d_in[9];
  const float* Wu        = (const float*)d_in[10];
  const float* bu        = (const float*)d_in[11];
  const float* Wp        = (const float*)d_in[12];
  const float* W_out     = (const float*)d_in[13];
  const float* b_out     = (const float*)d_in[14];
  const int*   ei        = (const int*)d_in[15];
  float* out = (float*)d_out;

  // workspace layout — verified non-overlapping (round-4 bug: src_s overlapped rowptr)
  char* ws = (char*)d_ws;
  float*          h     = (float*)(ws);                          //   0        .. 64 MB
  unsigned short* hbf   = (unsigned short*)(ws +  67108864UL);   //  64 MB     .. 96 MB
  unsigned short* X     = (unsigned short*)(ws + 100663296UL);   //  96 MB     .. 128 MB
  unsigned short* Zb    = (unsigned short*)(ws + 134217728UL);   // 128 MB     .. 160 MB
  unsigned short* aggb  = (unsigned short*)(ws + 167772160UL);   // 160 MB     .. 192 MB
  float*          posA  = (float*)(ws + 201326592UL);            // +768 KB
  float*          posB  = (float*)(ws + 202113024UL);            // +768 KB
  float*          g     = (float*)(ws + 202899456UL);            // +2 MB
  float*          h0    = (float*)(ws + 204996608UL);            // +32 KB
  float*          md    = (float*)(ws + 205029376UL);            // +8 KB
  unsigned short* Wt1   = (unsigned short*)(ws + 205037568UL);   // +512 KB (2 layers)
  unsigned short* Wut   = (unsigned short*)(ws + 205561856UL);   // +512 KB (2 layers)
  int*            deg   = (int*)(ws + 206086144UL);              // +256 KB
  int*            cur   = (int*)(ws + 206348288UL);              // +256 KB
  int*            bsum  = (int*)(ws + 206610432UL);              // +1 KB
  int*            rowptr= (int*)(ws + 206611456UL);              // +256 KB -> ends 206873600
  int*            src_s = (int*)(ws + 206873600UL);              // +1 MB   -> ends 207922176

  // ---- CSR (counting sort by dst) ----
  hipMemsetAsync(deg, 0, (size_t)NN_ * sizeof(int), stream);
  deg_kernel<<<E_ / 256, 256, 0, stream>>>(ei, deg);
  scan1_kernel<<<256, 256, 0, stream>>>(deg, bsum);
  scan2_kernel<<<1, 256, 0, stream>>>(bsum);
  scan3_kernel<<<256, 256, 0, stream>>>(deg, bsum, cur);
  hipMemcpyAsync(rowptr, cur, (size_t)NN_ * sizeof(int), hipMemcpyDeviceToDevice, stream);
  scatter_kernel<<<E_ / 256, 256, 0, stream>>>(ei, cur, src_s);

  // ---- weight conversion ----
  for (int l = 0; l < L_; ++l) {
    wconv1_kernel<<<512, 256, 0, stream>>>(Wm + (size_t)l * 513 * H_, Wt1 + (size_t)l * 131072);
    wconv_kernel<<<512, 256, 0, stream>>>(Wu + (size_t)l * 512 * H_, Wut + (size_t)l * 131072);
  }

  // ---- node/pos init ----
  h0_kernel<<<B_, 256, 0, stream>>>(x, W_in, b_in, h0);
  meand_kernel<<<N_, 256, 0, stream>>>(positions, md);
  g_kernel<<<N_, 256, 0, stream>>>(md, Wg1, bg1, Wg2, bg2, g);
  hinit_kernel<<<NN_ * 64 / 256, 256, 0, stream>>>(h0, g, h);
  posinit_kernel<<<NN_ * 3 / 256, 256, 0, stream>>>(positions, posA);
  hbf_kernel<<<NN_ * H_ / 8 / 256, 256, 0, stream>>>(h, hbf);

  float* pos_cur = posA;
  float* pos_nxt = posB;
  for (int l = 0; l < L_; ++l) {
    gemm1_mfma<<<dim3(NN_ / 64, 2), 256, 0, stream>>>(hbf, Wt1 + (size_t)l * 131072,
                                                      bm + (size_t)l * H_, X, Zb);
    edge_kernel<<<NN_ / 8 / 4, 256, 0, stream>>>(X, Zb, pos_cur, rowptr, src_s,
                                                 Wm + (size_t)l * 513 * H_ + 512 * H_,
                                                 Wp + (size_t)l * H_, aggb, pos_nxt);
    upd2_mfma<<<NN_ / 64, 256, 0, stream>>>(h, hbf, aggb, Wut + (size_t)l * 131072,
                                            bu + (size_t)l * H_);
    float* tmp = pos_cur; pos_cur = pos_nxt; pos_nxt = tmp;
  }

  out_kernel<<<NN_ * 64 / 256, 256, 0, stream>>>(h, W_out, b_out, out);
}